// Round 1
// baseline (9883.742 us; speedup 1.0000x reference)
//
#include <hip/hip_runtime.h>
#include <stdint.h>

typedef __attribute__((ext_vector_type(8))) short short8;
typedef __attribute__((ext_vector_type(4))) float f4;

#define B_ 64
#define T_ 512
#define E_ 512
#define H_ 512
#define GH 2048  // 4*H

static __device__ __forceinline__ uint16_t f2bf(float f) {
  uint32_t u = __builtin_bit_cast(uint32_t, f);
  uint32_t r = (u + 0x7FFFu + ((u >> 16) & 1u)) >> 16;
  return (uint16_t)r;
}
static __device__ __forceinline__ float bf2f(uint16_t b) {
  return __builtin_bit_cast(float, (uint32_t)b << 16);
}
static __device__ __forceinline__ float sigmoidf_(float x) {
  return 1.0f / (1.0f + __expf(-x));
}
static __device__ __forceinline__ float tanhf_(float x) {
  float e = __expf(-2.0f * fabsf(x));
  float t = (1.0f - e) / (1.0f + e);
  return __builtin_copysignf(t, x);
}

// ---------------- init: h0 -> bf16 hi/lo broadcast buffer (parity 0); zero flags
__global__ void k_init(const float* __restrict__ h0, uint16_t* __restrict__ hhi0,
                       uint16_t* __restrict__ hlo0, int* __restrict__ flags) {
  int i = blockIdx.x * 256 + threadIdx.x;
  if (i < B_ * H_) {
    float v = h0[i];
    uint16_t hi = f2bf(v);
    hhi0[i] = hi;
    hlo0[i] = f2bf(v - bf2f(hi));
  }
  if (i < 64) flags[i] = 0;
}

// ---------------- pre-projection GEMM: pre[(t-t0)*64+b][g] = emb[x[b,t]] . W_ih[g] + b_ih[g]+b_hh[g]
// 128x128 tile, BK=64, 4 waves, bf16 MFMA 16x16x32, XOR-swizzled LDS (16B granules).
__launch_bounds__(256)
__global__ void k_pre(const int* __restrict__ x, const float* __restrict__ emb,
                      const float* __restrict__ Wih, const float* __restrict__ bih,
                      const float* __restrict__ bhh, float* __restrict__ pre, int t0) {
  __shared__ uint16_t As[128 * 64];
  __shared__ uint16_t Bs[128 * 64];
  const int tid = threadIdx.x;
  const int tm = blockIdx.x >> 4;
  const int tn = blockIdx.x & 15;
  const int wid = tid >> 6, lane = tid & 63;
  const int wr = wid >> 1, wc = wid & 1;

  const int arow = tid >> 1;
  const int half = tid & 1;
  const int m = tm * 128 + arow;
  const int bb = m & 63;
  const int tt = t0 + (m >> 6);
  const int xid = x[bb * T_ + tt];
  const float* asrc = emb + (size_t)xid * E_ + half * 32;
  const float* bsrc = Wih + (size_t)(tn * 128 + arow) * E_ + half * 32;

  f4 acc[4][4];
#pragma unroll
  for (int a = 0; a < 4; ++a)
#pragma unroll
    for (int b = 0; b < 4; ++b) acc[a][b] = (f4){0.f, 0.f, 0.f, 0.f};

  for (int kk = 0; kk < 8; ++kk) {
    __syncthreads();
#pragma unroll
    for (int gi = 0; gi < 4; ++gi) {
      f4 a0 = *(const f4*)(asrc + kk * 64 + gi * 8);
      f4 a1 = *(const f4*)(asrc + kk * 64 + gi * 8 + 4);
      f4 b0 = *(const f4*)(bsrc + kk * 64 + gi * 8);
      f4 b1 = *(const f4*)(bsrc + kk * 64 + gi * 8 + 4);
      short8 va, vb;
#pragma unroll
      for (int j = 0; j < 4; ++j) {
        va[j] = (short)f2bf(a0[j]); va[4 + j] = (short)f2bf(a1[j]);
        vb[j] = (short)f2bf(b0[j]); vb[4 + j] = (short)f2bf(b1[j]);
      }
      int kq = half * 4 + gi;
      *(short8*)(As + arow * 64 + (kq ^ (arow & 7)) * 8) = va;
      *(short8*)(Bs + arow * 64 + (kq ^ (arow & 7)) * 8) = vb;
    }
    __syncthreads();
#pragma unroll
    for (int ks = 0; ks < 2; ++ks) {
      short8 af[4], bfr[4];
#pragma unroll
      for (int mi = 0; mi < 4; ++mi) {
        int row = wr * 64 + mi * 16 + (lane & 15);
        int kq = ks * 4 + (lane >> 4);
        af[mi] = *(const short8*)(As + row * 64 + (kq ^ (row & 7)) * 8);
      }
#pragma unroll
      for (int ni = 0; ni < 4; ++ni) {
        int row = wc * 64 + ni * 16 + (lane & 15);
        int kq = ks * 4 + (lane >> 4);
        bfr[ni] = *(const short8*)(Bs + row * 64 + (kq ^ (row & 7)) * 8);
      }
#pragma unroll
      for (int mi = 0; mi < 4; ++mi)
#pragma unroll
        for (int ni = 0; ni < 4; ++ni)
          acc[mi][ni] = __builtin_amdgcn_mfma_f32_16x16x32_bf16(af[mi], bfr[ni], acc[mi][ni], 0, 0, 0);
    }
  }
#pragma unroll
  for (int ni = 0; ni < 4; ++ni) {
    int n = tn * 128 + wc * 64 + ni * 16 + (lane & 15);
    float bias = bih[n] + bhh[n];
#pragma unroll
    for (int mi = 0; mi < 4; ++mi) {
      int mrow = tm * 128 + wr * 64 + mi * 16 + (lane >> 4) * 4;
#pragma unroll
      for (int j = 0; j < 4; ++j)
        __builtin_nontemporal_store(acc[mi][ni][j] + bias, &pre[(size_t)(mrow + j) * GH + n]);
    }
  }
}

// ---------------- persistent recurrence: 64 wgs (one per 8 hidden units, all 64 batches),
// W_hh slice resident in LDS as bf16 hi/lo (3-pass MFMA ~ fp32 accuracy),
// h broadcast via global bf16 hi/lo double buffer + per-wg flags (device-scope).
__launch_bounds__(256)
__global__ void k_lstm(const float* __restrict__ pre, const float* __restrict__ Whh,
                       const float* __restrict__ c0, float* __restrict__ out,
                       uint16_t* __restrict__ hhi0, uint16_t* __restrict__ hhi1,
                       uint16_t* __restrict__ hlo0, uint16_t* __restrict__ hlo1,
                       float* __restrict__ c_state, int* __restrict__ flags, int t0, int TB) {
  __shared__ uint16_t Wh[2 * 32 * 512];  // 64 KiB: [part][n=q*8+u][k], 16B-granule XOR swizzle
  const int tid = threadIdx.x;
  const int g = blockIdx.x;
  const int wid = tid >> 6;
  const int lane = tid & 63;
  const int nloc = lane & 15;
  const int hi4 = lane >> 4;

  // stage W_hh slice hi/lo
#pragma unroll
  for (int it = 0; it < 8; ++it) {
    int flat = tid + it * 256;  // 16B granule id, 2048 total
    int n = flat >> 6;          // 0..31
    int kq = flat & 63;         // granule in row
    int grow = (n >> 3) * 512 + g * 8 + (n & 7);
    const float* src = Whh + (size_t)grow * H_ + kq * 8;
    f4 w0 = *(const f4*)src;
    f4 w1 = *(const f4*)(src + 4);
    short8 vhi, vlo;
#pragma unroll
    for (int j = 0; j < 4; ++j) {
      uint16_t h0b = f2bf(w0[j]);
      vhi[j] = (short)h0b;
      vlo[j] = (short)f2bf(w0[j] - bf2f(h0b));
      uint16_t h1b = f2bf(w1[j]);
      vhi[4 + j] = (short)h1b;
      vlo[4 + j] = (short)f2bf(w1[j] - bf2f(h1b));
    }
    int kqs = (kq & ~7) | ((kq & 7) ^ (n & 7));
    *(short8*)(Wh + n * 512 + kqs * 8) = vhi;
    *(short8*)(Wh + 16384 + n * 512 + kqs * 8) = vlo;
  }

  const int u = g * 8 + (nloc & 7);
  float c_reg[4];
  {
    const float* csrc = (t0 == 0) ? c0 : c_state;
#pragma unroll
    for (int j = 0; j < 4; ++j) {
      int b = wid * 16 + hi4 * 4 + j;
      c_reg[j] = (nloc < 8) ? csrc[b * H_ + u] : 0.f;
    }
  }
  const int q0base = (nloc >> 3) * 512 + g * 8 + (nloc & 7);
  __syncthreads();

  for (int s = t0 + 1; s <= t0 + TB; ++s) {
    const uint16_t* hs_hi = (s & 1) ? hhi0 : hhi1;  // h_{s-1} parity (s-1)&1
    const uint16_t* hs_lo = (s & 1) ? hlo0 : hlo1;
    uint16_t* hd_hi = (s & 1) ? hhi1 : hhi0;
    uint16_t* hd_lo = (s & 1) ? hlo1 : hlo0;

    // prefetch pre-projection (independent of other wgs) before the wait
    float p0[4], p1[4];
    {
      const float* prow = pre + (size_t)(s - 1 - t0) * 64 * GH;
#pragma unroll
      for (int j = 0; j < 4; ++j) {
        int b = wid * 16 + hi4 * 4 + j;
        p0[j] = prow[b * GH + q0base];
        p1[j] = prow[b * GH + 1024 + q0base];
      }
    }
    {
      int target = s - 1;
      while (__hip_atomic_load(&flags[lane], __ATOMIC_RELAXED, __HIP_MEMORY_SCOPE_AGENT) < target)
        __builtin_amdgcn_s_sleep(1);
    }
    __threadfence();  // acquire: invalidate stale cached h lines

    f4 acc0 = {p0[0], p0[1], p0[2], p0[3]};  // cols 0..15 = i|f
    f4 acc1 = {p1[0], p1[1], p1[2], p1[3]};  // cols 16..31 = g|o

    const int arow = wid * 16 + nloc;
    const uint16_t* ahp = hs_hi + arow * H_ + hi4 * 8;
    const uint16_t* alp = hs_lo + arow * H_ + hi4 * 8;
    const int n0 = nloc;
    const int n1 = 16 + nloc;
#pragma unroll 4
    for (int ks = 0; ks < 16; ++ks) {
      short8 ah = *(const short8*)(ahp + ks * 32);
      short8 al = *(const short8*)(alp + ks * 32);
      int kq = ks * 4 + hi4;
      int kqs0 = (kq & ~7) | ((kq & 7) ^ (n0 & 7));
      int kqs1 = (kq & ~7) | ((kq & 7) ^ (n1 & 7));
      short8 bh0 = *(const short8*)(Wh + n0 * 512 + kqs0 * 8);
      short8 bl0 = *(const short8*)(Wh + 16384 + n0 * 512 + kqs0 * 8);
      short8 bh1 = *(const short8*)(Wh + n1 * 512 + kqs1 * 8);
      short8 bl1 = *(const short8*)(Wh + 16384 + n1 * 512 + kqs1 * 8);
      acc0 = __builtin_amdgcn_mfma_f32_16x16x32_bf16(ah, bh0, acc0, 0, 0, 0);
      acc0 = __builtin_amdgcn_mfma_f32_16x16x32_bf16(al, bh0, acc0, 0, 0, 0);
      acc0 = __builtin_amdgcn_mfma_f32_16x16x32_bf16(ah, bl0, acc0, 0, 0, 0);
      acc1 = __builtin_amdgcn_mfma_f32_16x16x32_bf16(ah, bh1, acc1, 0, 0, 0);
      acc1 = __builtin_amdgcn_mfma_f32_16x16x32_bf16(al, bh1, acc1, 0, 0, 0);
      acc1 = __builtin_amdgcn_mfma_f32_16x16x32_bf16(ah, bl1, acc1, 0, 0, 0);
    }

    float of0[4], of1[4];
#pragma unroll
    for (int j = 0; j < 4; ++j) {
      of0[j] = __shfl_xor(acc0[j], 8);
      of1[j] = __shfl_xor(acc1[j], 8);
    }
    if (nloc < 8) {
#pragma unroll
      for (int j = 0; j < 4; ++j) {
        float iv = sigmoidf_(acc0[j]);
        float fv = sigmoidf_(of0[j]);
        float gv = tanhf_(acc1[j]);
        float ov = sigmoidf_(of1[j]);
        float cn = fv * c_reg[j] + iv * gv;
        c_reg[j] = cn;
        float hn = ov * tanhf_(cn);
        int b = wid * 16 + hi4 * 4 + j;
        __builtin_nontemporal_store(hn, &out[(size_t)b * (T_ * H_) + (size_t)(s - 1) * H_ + u]);
        uint16_t hh = f2bf(hn);
        __builtin_nontemporal_store(hh, &hd_hi[b * H_ + u]);
        __builtin_nontemporal_store((uint16_t)f2bf(hn - bf2f(hh)), &hd_lo[b * H_ + u]);
      }
    }
    __threadfence();   // release: drain + make h slice device-visible
    __syncthreads();
    if (tid == 0)
      __hip_atomic_store(&flags[g], s, __ATOMIC_RELAXED, __HIP_MEMORY_SCOPE_AGENT);
  }

  if (nloc < 8) {
#pragma unroll
    for (int j = 0; j < 4; ++j) {
      int b = wid * 16 + hi4 * 4 + j;
      c_state[b * H_ + u] = c_reg[j];
    }
  }
}

extern "C" void kernel_launch(void* const* d_in, const int* in_sizes, int n_in,
                              void* d_out, int out_size, void* d_ws, size_t ws_size,
                              hipStream_t stream) {
  (void)in_sizes; (void)n_in; (void)out_size;
  const int* x = (const int*)d_in[0];
  const float* h0 = (const float*)d_in[1];
  const float* c0 = (const float*)d_in[2];
  const float* emb = (const float*)d_in[3];
  const float* Wih = (const float*)d_in[4];
  const float* Whh = (const float*)d_in[5];
  const float* bih = (const float*)d_in[6];
  const float* bhh = (const float*)d_in[7];
  float* out = (float*)d_out;
  char* ws = (char*)d_ws;

  int* flags = (int*)ws;                                  // 4 KiB
  float* c_state = (float*)(ws + 4096);                   // 128 KiB (+pad)
  uint16_t* hhi0 = (uint16_t*)(ws + 139264);              // 4 x 64 KiB h broadcast
  uint16_t* hhi1 = (uint16_t*)(ws + 139264 + 65536);
  uint16_t* hlo0 = (uint16_t*)(ws + 139264 + 2 * 65536);
  uint16_t* hlo1 = (uint16_t*)(ws + 139264 + 3 * 65536);
  float* pre = (float*)(ws + 401408);                     // TB*64*2048 fp32

  int TB = 512;
  while (TB > 2 && (size_t)401408 + (size_t)TB * 64 * 2048 * 4 > ws_size) TB >>= 1;

  k_init<<<dim3(128), dim3(256), 0, stream>>>(h0, hhi0, hlo0, flags);
  for (int t0 = 0; t0 < 512; t0 += TB) {
    k_pre<<<dim3((TB * 64 / 128) * 16), dim3(256), 0, stream>>>(x, emb, Wih, bih, bhh, pre, t0);
    k_lstm<<<dim3(64), dim3(256), 0, stream>>>(pre, Whh, c0, out, hhi0, hhi1, hlo0, hlo1,
                                               c_state, flags, t0, TB);
  }
}

// Round 2
// 5024.380 us; speedup vs baseline: 1.9672x; 1.9672x over previous
//
#include <hip/hip_runtime.h>
#include <stdint.h>

typedef __attribute__((ext_vector_type(8))) short short8;
typedef __attribute__((ext_vector_type(4))) float f4;
typedef __attribute__((ext_vector_type(4))) uint32_t u32x4;

#define B_ 64
#define T_ 512
#define E_ 512
#define H_ 512
#define GH 2048  // 4*H

static __device__ __forceinline__ uint16_t f2bf(float f) {
  uint32_t u = __builtin_bit_cast(uint32_t, f);
  uint32_t r = (u + 0x7FFFu + ((u >> 16) & 1u)) >> 16;
  return (uint16_t)r;
}
static __device__ __forceinline__ float bf2f(uint16_t b) {
  return __builtin_bit_cast(float, (uint32_t)b << 16);
}
static __device__ __forceinline__ float sigmoidf_(float x) {
  return 1.0f / (1.0f + __expf(-x));
}
static __device__ __forceinline__ float tanhf_(float x) {
  float e = __expf(-2.0f * fabsf(x));
  float t = (1.0f - e) / (1.0f + e);
  return __builtin_copysignf(t, x);
}

// ---------------- prep: split W_hh fp32 -> bf16 hi + bf16 lo in ws
__global__ void k_prep(const float* __restrict__ Whh, uint16_t* __restrict__ Whi_g,
                       uint16_t* __restrict__ Wlo_g) {
  int i = blockIdx.x * 256 + threadIdx.x;  // 4096 blocks -> 1M elems
  float w = Whh[i];
  uint16_t hi = f2bf(w);
  Whi_g[i] = hi;
  Wlo_g[i] = f2bf(w - bf2f(hi));
}

// ---------------- init: h0 -> packed (hi | lo<<16) parity-0 broadcast buffer; zero flags
__global__ void k_init(const float* __restrict__ h0, uint32_t* __restrict__ hP0,
                       int* __restrict__ flags) {
  int i = blockIdx.x * 256 + threadIdx.x;
  if (i < B_ * H_) {
    float v = h0[i];
    uint16_t hi = f2bf(v);
    uint16_t lo = f2bf(v - bf2f(hi));
    hP0[i] = (uint32_t)hi | ((uint32_t)lo << 16);
  }
  if (i < 2048) flags[i] = 0;
}

// ---------------- pre-projection GEMM (unchanged from round 1, verified)
__launch_bounds__(256)
__global__ void k_pre(const int* __restrict__ x, const float* __restrict__ emb,
                      const float* __restrict__ Wih, const float* __restrict__ bih,
                      const float* __restrict__ bhh, float* __restrict__ pre, int t0) {
  __shared__ uint16_t As[128 * 64];
  __shared__ uint16_t Bs[128 * 64];
  const int tid = threadIdx.x;
  const int tm = blockIdx.x >> 4;
  const int tn = blockIdx.x & 15;
  const int wid = tid >> 6, lane = tid & 63;
  const int wr = wid >> 1, wc = wid & 1;

  const int arow = tid >> 1;
  const int half = tid & 1;
  const int m = tm * 128 + arow;
  const int bb = m & 63;
  const int tt = t0 + (m >> 6);
  const int xid = x[bb * T_ + tt];
  const float* asrc = emb + (size_t)xid * E_ + half * 32;
  const float* bsrc = Wih + (size_t)(tn * 128 + arow) * E_ + half * 32;

  f4 acc[4][4];
#pragma unroll
  for (int a = 0; a < 4; ++a)
#pragma unroll
    for (int b = 0; b < 4; ++b) acc[a][b] = (f4){0.f, 0.f, 0.f, 0.f};

  for (int kk = 0; kk < 8; ++kk) {
    __syncthreads();
#pragma unroll
    for (int gi = 0; gi < 4; ++gi) {
      f4 a0 = *(const f4*)(asrc + kk * 64 + gi * 8);
      f4 a1 = *(const f4*)(asrc + kk * 64 + gi * 8 + 4);
      f4 b0 = *(const f4*)(bsrc + kk * 64 + gi * 8);
      f4 b1 = *(const f4*)(bsrc + kk * 64 + gi * 8 + 4);
      short8 va, vb;
#pragma unroll
      for (int j = 0; j < 4; ++j) {
        va[j] = (short)f2bf(a0[j]); va[4 + j] = (short)f2bf(a1[j]);
        vb[j] = (short)f2bf(b0[j]); vb[4 + j] = (short)f2bf(b1[j]);
      }
      int kq = half * 4 + gi;
      *(short8*)(As + arow * 64 + (kq ^ (arow & 7)) * 8) = va;
      *(short8*)(Bs + arow * 64 + (kq ^ (arow & 7)) * 8) = vb;
    }
    __syncthreads();
#pragma unroll
    for (int ks = 0; ks < 2; ++ks) {
      short8 af[4], bfr[4];
#pragma unroll
      for (int mi = 0; mi < 4; ++mi) {
        int row = wr * 64 + mi * 16 + (lane & 15);
        int kq = ks * 4 + (lane >> 4);
        af[mi] = *(const short8*)(As + row * 64 + (kq ^ (row & 7)) * 8);
      }
#pragma unroll
      for (int ni = 0; ni < 4; ++ni) {
        int row = wc * 64 + ni * 16 + (lane & 15);
        int kq = ks * 4 + (lane >> 4);
        bfr[ni] = *(const short8*)(Bs + row * 64 + (kq ^ (row & 7)) * 8);
      }
#pragma unroll
      for (int mi = 0; mi < 4; ++mi)
#pragma unroll
        for (int ni = 0; ni < 4; ++ni)
          acc[mi][ni] = __builtin_amdgcn_mfma_f32_16x16x32_bf16(af[mi], bfr[ni], acc[mi][ni], 0, 0, 0);
    }
  }
#pragma unroll
  for (int ni = 0; ni < 4; ++ni) {
    int n = tn * 128 + wc * 64 + ni * 16 + (lane & 15);
    float bias = bih[n] + bhh[n];
#pragma unroll
    for (int mi = 0; mi < 4; ++mi) {
      int mrow = tm * 128 + wr * 64 + mi * 16 + (lane >> 4) * 4;
#pragma unroll
      for (int j = 0; j < 4; ++j)
        __builtin_nontemporal_store(acc[mi][ni][j] + bias, &pre[(size_t)(mrow + j) * GH + n]);
    }
  }
}

// ---------------- persistent recurrence, fence-free.
// 64 wgs = 2 batch-groups x 32 unit-groups. wg: 32 batches x 16 units (64 gate rows).
// W_hi bf16 in LDS (swizzled), W_lo bf16 from L2, h hi/lo staged in LDS per step.
// Cross-wg h exchange: packed u32 (bf16 hi | lo<<16) via relaxed agent-scope atomics
// (sc0 sc1 loads/stores, NO buffer_wbl2/buffer_inv). Flags: relaxed agent atomics;
// store-ordering via the compiler's vmcnt(0)-before-s_barrier drain.
__launch_bounds__(256)
__global__ void k_lstm(const float* __restrict__ pre, const uint16_t* __restrict__ Whi_g,
                       const uint16_t* __restrict__ Wlo_g, const float* __restrict__ c0,
                       float* __restrict__ out, uint32_t* __restrict__ hP0,
                       uint32_t* __restrict__ hP1, float* __restrict__ c_state,
                       int* __restrict__ flags, int t0, int TB) {
  extern __shared__ char smem[];
  uint16_t* Wh = (uint16_t*)smem;             // [64][512] bf16, granule-swizzled (64 KiB)
  uint16_t* Hh = (uint16_t*)(smem + 65536);   // [32][512] h hi (32 KiB)
  uint16_t* Hl = (uint16_t*)(smem + 98304);   // [32][512] h lo (32 KiB)

  const int tid = threadIdx.x;
  const int bg = blockIdx.x >> 5;   // batch group (0,1)
  const int ug = blockIdx.x & 31;   // unit group (16 units)
  const int wv = tid >> 6, lane = tid & 63;
  const int wi = lane & 15, hi4 = lane >> 4;
  const int q = wi & 3, v = wi >> 2;           // gate, unit-within-4
  const int wm = wv >> 1;                      // wave m-tile (16 batches)
  const int wn = wv & 1;                       // wave n-half (2 n-tiles)
  const int u0 = ug * 16 + (wn * 2 + 0) * 4 + v;
  const int u1 = ug * 16 + (wn * 2 + 1) * 4 + v;
  const int gu0 = q * 512 + u0;                // W/pre row-col for n-tile 0
  const int gu1 = q * 512 + u1;

  // ---- stage W_hi slice into LDS (4096 x 16B granules)
  for (int it = 0; it < 16; ++it) {
    int gr = it * 256 + tid;
    int r = gr >> 6, kq = gr & 63;
    int grow = (r & 3) * 512 + ug * 16 + (r >> 4) * 4 + ((r >> 2) & 3);
    short8 w8 = *(const short8*)(Whi_g + (size_t)grow * 512 + kq * 8);
    int kqs = (kq & ~7) | ((kq & 7) ^ (r & 7));
    *(short8*)(Wh + r * 512 + kqs * 8) = w8;
  }

  // ---- c init (each quad lane keeps full f4, duplicated across quad)
  f4 c_reg0, c_reg1;
  {
    const float* csrc = (t0 == 0) ? c0 : c_state;
    const int brow = bg * 32 + wm * 16 + hi4 * 4;
#pragma unroll
    for (int j = 0; j < 4; ++j) {
      c_reg0[j] = csrc[(size_t)(brow + j) * H_ + u0];
      c_reg1[j] = csrc[(size_t)(brow + j) * H_ + u1];
    }
  }
  const uint16_t* wlo0 = Wlo_g + (size_t)gu0 * 512 + hi4 * 8;
  const uint16_t* wlo1 = Wlo_g + (size_t)gu1 * 512 + hi4 * 8;
  __syncthreads();

  for (int s = t0 + 1; s <= t0 + TB; ++s) {
    const uint32_t* hsrc = (s & 1) ? hP0 : hP1;  // holds h_{s-1}
    uint32_t* hdst = (s & 1) ? hP1 : hP0;        // receives h_s

    // prefetch pre-projection (wg-private, independent of flags)
    f4 accA0, accA1, accB0, accB1, accC0, accC1;
    {
      const float* prow = pre + (size_t)(s - 1 - t0) * (64 * GH) +
                          (size_t)(bg * 32 + wm * 16 + hi4 * 4) * GH;
#pragma unroll
      for (int j = 0; j < 4; ++j) {
        accA0[j] = prow[j * GH + gu0];
        accA1[j] = prow[j * GH + gu1];
      }
      accB0 = (f4){0.f, 0.f, 0.f, 0.f}; accB1 = accB0;
      accC0 = accB0; accC1 = accB0;
    }

    // wait for all 32 sibling wgs of this batch group to have published h_{s-1}
    if (lane < 32) {
      const int* fp = flags + (bg * 32 + lane) * 32;
      while (__hip_atomic_load(fp, __ATOMIC_RELAXED, __HIP_MEMORY_SCOPE_AGENT) < s - 1)
        __builtin_amdgcn_s_sleep(2);
    }

    // stage h_{s-1} (this bg's 32 rows) into LDS, unpacking hi/lo
    for (int it = 0; it < 8; ++it) {
      int fl = it * 256 + tid;
      int r = fl >> 6, kq = fl & 63;
      const unsigned long long* src =
          (const unsigned long long*)(hsrc + (size_t)(bg * 32 + r) * 512 + kq * 8);
      unsigned long long d0 = __hip_atomic_load(src + 0, __ATOMIC_RELAXED, __HIP_MEMORY_SCOPE_AGENT);
      unsigned long long d1 = __hip_atomic_load(src + 1, __ATOMIC_RELAXED, __HIP_MEMORY_SCOPE_AGENT);
      unsigned long long d2 = __hip_atomic_load(src + 2, __ATOMIC_RELAXED, __HIP_MEMORY_SCOPE_AGENT);
      unsigned long long d3 = __hip_atomic_load(src + 3, __ATOMIC_RELAXED, __HIP_MEMORY_SCOPE_AGENT);
      u32x4 vh, vl;
      {
        uint32_t a0 = (uint32_t)d0, b0 = (uint32_t)(d0 >> 32);
        vh.x = (a0 & 0xFFFFu) | (b0 << 16); vl.x = (a0 >> 16) | (b0 & 0xFFFF0000u);
        uint32_t a1 = (uint32_t)d1, b1 = (uint32_t)(d1 >> 32);
        vh.y = (a1 & 0xFFFFu) | (b1 << 16); vl.y = (a1 >> 16) | (b1 & 0xFFFF0000u);
        uint32_t a2 = (uint32_t)d2, b2 = (uint32_t)(d2 >> 32);
        vh.z = (a2 & 0xFFFFu) | (b2 << 16); vl.z = (a2 >> 16) | (b2 & 0xFFFF0000u);
        uint32_t a3 = (uint32_t)d3, b3 = (uint32_t)(d3 >> 32);
        vh.w = (a3 & 0xFFFFu) | (b3 << 16); vl.w = (a3 >> 16) | (b3 & 0xFFFF0000u);
      }
      int kqs = (kq & ~7) | ((kq & 7) ^ (r & 7));
      *(u32x4*)(Hh + r * 512 + kqs * 8) = vh;
      *(u32x4*)(Hl + r * 512 + kqs * 8) = vl;
    }
    __syncthreads();

    // MFMA: 3-pass bf16 hi/lo (~fp32): acc = p + Ah*Bh + Al*Bh + Ah*Bl
    const int arow = wm * 16 + wi;
    const int br0 = (wn * 2 + 0) * 16 + wi;
    const int br1 = (wn * 2 + 1) * 16 + wi;
#pragma unroll 4
    for (int ks = 0; ks < 16; ++ks) {
      int kq = ks * 4 + hi4;
      int kqsA = (kq & ~7) | ((kq & 7) ^ (arow & 7));
      int kqs0 = (kq & ~7) | ((kq & 7) ^ (br0 & 7));
      int kqs1 = (kq & ~7) | ((kq & 7) ^ (br1 & 7));
      short8 ah = *(const short8*)(Hh + arow * 512 + kqsA * 8);
      short8 al = *(const short8*)(Hl + arow * 512 + kqsA * 8);
      short8 bh0 = *(const short8*)(Wh + br0 * 512 + kqs0 * 8);
      short8 bh1 = *(const short8*)(Wh + br1 * 512 + kqs1 * 8);
      short8 bl0 = *(const short8*)(wlo0 + ks * 32);
      short8 bl1 = *(const short8*)(wlo1 + ks * 32);
      accA0 = __builtin_amdgcn_mfma_f32_16x16x32_bf16(ah, bh0, accA0, 0, 0, 0);
      accA1 = __builtin_amdgcn_mfma_f32_16x16x32_bf16(ah, bh1, accA1, 0, 0, 0);
      accB0 = __builtin_amdgcn_mfma_f32_16x16x32_bf16(al, bh0, accB0, 0, 0, 0);
      accB1 = __builtin_amdgcn_mfma_f32_16x16x32_bf16(al, bh1, accB1, 0, 0, 0);
      accC0 = __builtin_amdgcn_mfma_f32_16x16x32_bf16(ah, bl0, accC0, 0, 0, 0);
      accC1 = __builtin_amdgcn_mfma_f32_16x16x32_bf16(ah, bl1, accC1, 0, 0, 0);
    }

    // gate combine (quad butterfly), pointwise, publish
    const bool qb0 = (q & 1) != 0, qb1 = (q & 2) != 0;
    const int b = bg * 32 + wm * 16 + hi4 * 4 + q;
#pragma unroll
    for (int t = 0; t < 2; ++t) {
      f4 a0;
#pragma unroll
      for (int j = 0; j < 4; ++j)
        a0[j] = t ? (accA1[j] + accB1[j] + accC1[j]) : (accA0[j] + accB0[j] + accC0[j]);
      f4 x1, s1a, s1b, x2a, x2b;
#pragma unroll
      for (int j = 0; j < 4; ++j) x1[j] = __shfl_xor(a0[j], 1);
#pragma unroll
      for (int j = 0; j < 4; ++j) {
        s1a[j] = qb0 ? x1[j] : a0[j];
        s1b[j] = qb0 ? a0[j] : x1[j];
      }
#pragma unroll
      for (int j = 0; j < 4; ++j) {
        x2a[j] = __shfl_xor(s1a[j], 2);
        x2b[j] = __shfl_xor(s1b[j], 2);
      }
      f4 cn, hn;
#pragma unroll
      for (int j = 0; j < 4; ++j) {
        float gi = qb1 ? x2a[j] : s1a[j];
        float gg = qb1 ? s1a[j] : x2a[j];
        float gf = qb1 ? x2b[j] : s1b[j];
        float go = qb1 ? s1b[j] : x2b[j];
        float iv = sigmoidf_(gi);
        float fv = sigmoidf_(gf);
        float gv = tanhf_(gg);
        float ov = sigmoidf_(go);
        float cp = t ? c_reg1[j] : c_reg0[j];
        float c2 = fv * cp + iv * gv;
        cn[j] = c2;
        hn[j] = ov * tanhf_(c2);
      }
      if (t) c_reg1 = cn; else c_reg0 = cn;
      float s01 = qb0 ? hn[1] : hn[0];
      float s23 = qb0 ? hn[3] : hn[2];
      float hq = qb1 ? s23 : s01;
      int uu = t ? u1 : u0;
      __builtin_nontemporal_store(hq, &out[(size_t)b * (T_ * H_) + (size_t)(s - 1) * H_ + uu]);
      uint16_t hhi = f2bf(hq);
      uint16_t hlo = f2bf(hq - bf2f(hhi));
      __hip_atomic_store(&hdst[(size_t)b * 512 + uu], (uint32_t)hhi | ((uint32_t)hlo << 16),
                         __ATOMIC_RELAXED, __HIP_MEMORY_SCOPE_AGENT);
    }
    __syncthreads();  // compiler drains vmcnt(0): all waves' h stores at coherence point
    if (tid == 0)
      __hip_atomic_store(&flags[blockIdx.x * 32], s, __ATOMIC_RELAXED, __HIP_MEMORY_SCOPE_AGENT);
  }

  // persist c for chunked launches
  {
    const bool qb0 = (q & 1) != 0, qb1 = (q & 2) != 0;
    const int b = bg * 32 + wm * 16 + hi4 * 4 + q;
    float c01 = qb0 ? c_reg0[1] : c_reg0[0];
    float c23 = qb0 ? c_reg0[3] : c_reg0[2];
    c_state[(size_t)b * H_ + u0] = qb1 ? c23 : c01;
    float d01 = qb0 ? c_reg1[1] : c_reg1[0];
    float d23 = qb0 ? c_reg1[3] : c_reg1[2];
    c_state[(size_t)b * H_ + u1] = qb1 ? d23 : d01;
  }
}

extern "C" void kernel_launch(void* const* d_in, const int* in_sizes, int n_in,
                              void* d_out, int out_size, void* d_ws, size_t ws_size,
                              hipStream_t stream) {
  (void)in_sizes; (void)n_in; (void)out_size;
  const int* x = (const int*)d_in[0];
  const float* h0 = (const float*)d_in[1];
  const float* c0 = (const float*)d_in[2];
  const float* emb = (const float*)d_in[3];
  const float* Wih = (const float*)d_in[4];
  const float* Whh = (const float*)d_in[5];
  const float* bih = (const float*)d_in[6];
  const float* bhh = (const float*)d_in[7];
  float* out = (float*)d_out;
  char* ws = (char*)d_ws;

  int* flags = (int*)ws;                        // 8 KiB (64 flags, 128B stride)
  float* c_state = (float*)(ws + 8192);         // 128 KiB
  uint32_t* hP0 = (uint32_t*)(ws + 139264);     // 128 KiB packed h (parity 0)
  uint32_t* hP1 = (uint32_t*)(ws + 270336);     // 128 KiB packed h (parity 1)
  uint16_t* Whi_g = (uint16_t*)(ws + 401408);   // 2 MiB
  uint16_t* Wlo_g = (uint16_t*)(ws + 2498560);  // 2 MiB
  float* pre = (float*)(ws + 4595712);          // TB*64*2048 fp32

  int TB = 512;
  while (TB > 2 && (size_t)4595712 + (size_t)TB * 64 * 2048 * 4 > ws_size) TB >>= 1;

  (void)hipFuncSetAttribute(reinterpret_cast<const void*>(k_lstm),
                            hipFuncAttributeMaxDynamicSharedMemorySize, 131072);

  k_prep<<<dim3(4096), dim3(256), 0, stream>>>(Whh, Whi_g, Wlo_g);
  k_init<<<dim3(128), dim3(256), 0, stream>>>(h0, hP0, flags);
  for (int t0 = 0; t0 < 512; t0 += TB) {
    k_pre<<<dim3((TB * 64 / 128) * 16), dim3(256), 0, stream>>>(x, emb, Wih, bih, bhh, pre, t0);
    k_lstm<<<dim3(64), dim3(256), 131072, stream>>>(pre, Whi_g, Wlo_g, c0, out, hP0, hP1,
                                                    c_state, flags, t0, TB);
  }
}

// Round 5
// 2483.793 us; speedup vs baseline: 3.9793x; 2.0229x over previous
//
#include <hip/hip_runtime.h>
#include <stdint.h>

typedef __attribute__((ext_vector_type(8))) short short8;
typedef __attribute__((ext_vector_type(4))) float f4;
typedef __attribute__((ext_vector_type(4))) uint32_t u32x4;

#define B_ 64
#define T_ 512
#define E_ 512
#define H_ 512
#define GH 2048  // 4*H

static __device__ __forceinline__ uint16_t f2bf(float f) {
  uint32_t u = __builtin_bit_cast(uint32_t, f);
  uint32_t r = (u + 0x7FFFu + ((u >> 16) & 1u)) >> 16;
  return (uint16_t)r;
}
static __device__ __forceinline__ float bf2f(uint16_t b) {
  return __builtin_bit_cast(float, (uint32_t)b << 16);
}
static __device__ __forceinline__ float sigmoidf_(float x) {
  return 1.0f / (1.0f + __expf(-x));
}
static __device__ __forceinline__ float tanhf_(float x) {
  float e = __expf(-2.0f * fabsf(x));
  float t = (1.0f - e) / (1.0f + e);
  return __builtin_copysignf(t, x);
}

// ---- L3-coherent (agent) access helpers: sc0 sc1 = bypass L1+L2, coherence at L3.
// Same coherence point as the round-2 proven __hip_atomic_* protocol, but batchable.
static __device__ __forceinline__ int ld_flag_cc(const int* p) {
  int v;
  asm volatile("global_load_dword %0, %1, off sc0 sc1\n\ts_waitcnt vmcnt(0)"
               : "=v"(v) : "v"(p) : "memory");
  return v;
}
static __device__ __forceinline__ void ld_x4_cc(u32x4* d, const void* p) {
  asm volatile("global_load_dwordx4 %0, %1, off sc0 sc1" : "=v"(*d) : "v"(p));
}
static __device__ __forceinline__ void st_u16_cc(uint16_t* p, uint32_t v) {
  asm volatile("global_store_short %0, %1, off sc0 sc1" :: "v"(p), "v"(v) : "memory");
}
static __device__ __forceinline__ void st_flag_cc(int* p, int v) {
  asm volatile("global_store_dword %0, %1, off sc0 sc1" :: "v"(p), "v"(v) : "memory");
}

// ---------------- prep: split W_hh fp32 -> bf16 hi + bf16 lo
__global__ void k_prep(const float* __restrict__ Whh, uint16_t* __restrict__ Whi_g,
                       uint16_t* __restrict__ Wlo_g) {
  int i = blockIdx.x * 256 + threadIdx.x;
  float w = Whh[i];
  uint16_t hi = f2bf(w);
  Whi_g[i] = hi;
  Wlo_g[i] = f2bf(w - bf2f(hi));
}

// ---------------- init: h0 -> hi/lo u16 buffers (parity 0); zero flags
__global__ void k_init(const float* __restrict__ h0, uint16_t* __restrict__ hHi0,
                       uint16_t* __restrict__ hLo0, int* __restrict__ flags) {
  int i = blockIdx.x * 256 + threadIdx.x;
  if (i < B_ * H_) {
    float v = h0[i];
    uint16_t hi = f2bf(v);
    hHi0[i] = hi;
    hLo0[i] = f2bf(v - bf2f(hi));
  }
  if (i < 128) flags[i] = 0;
}

// ---------------- pre-projection GEMM. Output layout: per-consumer blocks
// pre2[((t_rel*32 + ug)*4 + bg)*1024 + g_loc*16 + b_loc], g_loc = q*16 + u_loc.
__launch_bounds__(256)
__global__ void k_pre(const int* __restrict__ x, const float* __restrict__ emb,
                      const float* __restrict__ Wih, const float* __restrict__ bih,
                      const float* __restrict__ bhh, float* __restrict__ pre2, int t0) {
  __shared__ uint16_t As[128 * 64];
  __shared__ uint16_t Bs[128 * 64];
  const int tid = threadIdx.x;
  const int tm = blockIdx.x >> 4;
  const int tn = blockIdx.x & 15;
  const int wid = tid >> 6, lane = tid & 63;
  const int wr = wid >> 1, wc = wid & 1;

  const int arow = tid >> 1;
  const int half = tid & 1;
  const int m = tm * 128 + arow;
  const int bb = m & 63;
  const int tt = t0 + (m >> 6);
  const int xid = x[bb * T_ + tt];
  const float* asrc = emb + (size_t)xid * E_ + half * 32;
  const float* bsrc = Wih + (size_t)(tn * 128 + arow) * E_ + half * 32;

  f4 acc[4][4];
#pragma unroll
  for (int a = 0; a < 4; ++a)
#pragma unroll
    for (int b = 0; b < 4; ++b) acc[a][b] = (f4){0.f, 0.f, 0.f, 0.f};

  for (int kk = 0; kk < 8; ++kk) {
    __syncthreads();
#pragma unroll
    for (int gi = 0; gi < 4; ++gi) {
      f4 a0 = *(const f4*)(asrc + kk * 64 + gi * 8);
      f4 a1 = *(const f4*)(asrc + kk * 64 + gi * 8 + 4);
      f4 b0 = *(const f4*)(bsrc + kk * 64 + gi * 8);
      f4 b1 = *(const f4*)(bsrc + kk * 64 + gi * 8 + 4);
      short8 va, vb;
#pragma unroll
      for (int j = 0; j < 4; ++j) {
        va[j] = (short)f2bf(a0[j]); va[4 + j] = (short)f2bf(a1[j]);
        vb[j] = (short)f2bf(b0[j]); vb[4 + j] = (short)f2bf(b1[j]);
      }
      int kq = half * 4 + gi;
      *(short8*)(As + arow * 64 + (kq ^ (arow & 7)) * 8) = va;
      *(short8*)(Bs + arow * 64 + (kq ^ (arow & 7)) * 8) = vb;
    }
    __syncthreads();
#pragma unroll
    for (int ks = 0; ks < 2; ++ks) {
      short8 af[4], bfr[4];
#pragma unroll
      for (int mi = 0; mi < 4; ++mi) {
        int row = wr * 64 + mi * 16 + (lane & 15);
        int kq = ks * 4 + (lane >> 4);
        af[mi] = *(const short8*)(As + row * 64 + (kq ^ (row & 7)) * 8);
      }
#pragma unroll
      for (int ni = 0; ni < 4; ++ni) {
        int row = wc * 64 + ni * 16 + (lane & 15);
        int kq = ks * 4 + (lane >> 4);
        bfr[ni] = *(const short8*)(Bs + row * 64 + (kq ^ (row & 7)) * 8);
      }
#pragma unroll
      for (int mi = 0; mi < 4; ++mi)
#pragma unroll
        for (int ni = 0; ni < 4; ++ni)
          acc[mi][ni] = __builtin_amdgcn_mfma_f32_16x16x32_bf16(af[mi], bfr[ni], acc[mi][ni], 0, 0, 0);
    }
  }
#pragma unroll
  for (int ni = 0; ni < 4; ++ni) {
    int n = tn * 128 + wc * 64 + ni * 16 + (lane & 15);
    float bias = bih[n] + bhh[n];
    int q = n >> 9, u = n & 511;
    int ug = u >> 4, uloc = u & 15;
    int gl = q * 16 + uloc;
#pragma unroll
    for (int mi = 0; mi < 4; ++mi) {
      int mrow = tm * 128 + wr * 64 + mi * 16 + (lane >> 4) * 4;
      int trel = mrow >> 6;
      int bbr = mrow & 63;
      f4 vst;
#pragma unroll
      for (int j = 0; j < 4; ++j) vst[j] = acc[mi][ni][j] + bias;
      float* dst = pre2 + (((size_t)trel * 32 + ug) * 4 + (bbr >> 4)) * 1024 + gl * 16 + (bbr & 15);
      *(f4*)dst = vst;
    }
  }
}

// ---------------- persistent recurrence. 128 wgs = 4 batch-groups(16 rows) x 32
// unit-groups(16 units). 1 wg/CU (160 KiB LDS) on 128 of 256 CUs -> co-residency by
// CAPACITY (no dispatcher assumptions, no claims). W hi+lo in LDS; h hi/lo staged in
// LDS; exchange via batched sc0 sc1 loads/stores at L3 (round-2-proven ordering:
// stores -> vmcnt(0) -> barrier -> flag; consumers: poll flag line -> batched loads).
// All polls BOUNDED: protocol failure => wrong answer (absmax), never a GPU wedge.
__launch_bounds__(256)
__global__ void k_lstm(const float* __restrict__ pre2, const uint16_t* __restrict__ Whi_g,
                       const uint16_t* __restrict__ Wlo_g, const float* __restrict__ c0,
                       float* __restrict__ out, uint16_t* __restrict__ hHi0,
                       uint16_t* __restrict__ hHi1, uint16_t* __restrict__ hLo0,
                       uint16_t* __restrict__ hLo1, float* __restrict__ c_state,
                       int* __restrict__ flags, int t0, int TB) {
  extern __shared__ char smem[];
  uint16_t* WhiL = (uint16_t*)smem;              // [64][512] 64 KiB
  uint16_t* WloL = (uint16_t*)(smem + 65536);    // [64][512] 64 KiB
  uint16_t* Hh   = (uint16_t*)(smem + 131072);   // [16][512] 16 KiB
  uint16_t* Hl   = (uint16_t*)(smem + 147456);   // [16][512] 16 KiB

  const int tid = threadIdx.x;
  const int bg = blockIdx.x & 3;    // batch group (16 batches)
  const int ug = blockIdx.x >> 2;   // unit group (16 units)
  const int wv = tid >> 6, lane = tid & 63;
  const int wi = lane & 15, hi4 = lane >> 4;
  const int q = wi & 3, v = wi >> 2;
  const int u = ug * 16 + wv * 4 + v;   // this lane's unit
  const int gl = q * 16 + wv * 4 + v;   // g_loc in pre2 block

  // stage W hi/lo slice (64 gate-rows x 512) into LDS, 16B-granule XOR swizzle
  for (int it = 0; it < 16; ++it) {
    int gg = it * 256 + tid;  // 0..4095 granules
    int r = gg >> 6, kq = gg & 63;
    int grow = (r & 3) * 512 + ug * 16 + (r >> 4) * 4 + ((r >> 2) & 3);
    short8 whi = *(const short8*)(Whi_g + (size_t)grow * 512 + kq * 8);
    short8 wlo = *(const short8*)(Wlo_g + (size_t)grow * 512 + kq * 8);
    int kqs = (kq & ~7) | ((kq & 7) ^ (r & 7));
    *(short8*)(WhiL + r * 512 + kqs * 8) = whi;
    *(short8*)(WloL + r * 512 + kqs * 8) = wlo;
  }

  f4 c_reg;
  {
    const float* csrc = (t0 == 0) ? c0 : c_state;
    const int brow = bg * 16 + hi4 * 4;
#pragma unroll
    for (int j = 0; j < 4; ++j) c_reg[j] = csrc[(size_t)(brow + j) * H_ + u];
  }
  int* myflag = flags + bg * 32 + ug;
  __syncthreads();

  for (int s = t0 + 1; s <= t0 + TB; ++s) {
    // h_{t} lives in buffer[t&1]
    const uint16_t* hsHi = (((s - 1) & 1) ? hHi1 : hHi0) + (size_t)bg * 16 * 512;
    const uint16_t* hsLo = (((s - 1) & 1) ? hLo1 : hLo0) + (size_t)bg * 16 * 512;
    uint16_t* hdHi = ((s & 1) ? hHi1 : hHi0) + (size_t)bg * 16 * 512;
    uint16_t* hdLo = ((s & 1) ? hLo1 : hLo0) + (size_t)bg * 16 * 512;

    // prefetch this wg's 4 KiB pre2 block fragment (wg-private, plain load)
    f4 accA, accB, accC;
    {
      const float* pblk = pre2 + (((size_t)(s - 1 - t0) * 32 + ug) * 4 + bg) * 1024;
      accA = *(const f4*)(pblk + gl * 16 + hi4 * 4);
      accB = (f4){0.f, 0.f, 0.f, 0.f};
      accC = accB;
    }

    // wait for the 32 sibling wgs of this batch group (one 128B flag line).
    // BOUNDED spin: worst case ~0.1 s then proceed (wrong answer, not a hang).
    if (lane < 32) {
      const int* fp = flags + bg * 32 + lane;
      const int target = s - 1;
      int guard = 0;
      while (ld_flag_cc(fp) < target) {
        __builtin_amdgcn_s_sleep(1);
        if (++guard > (1 << 20)) break;
      }
    }

    // gather h_{s-1} (16 rows x 512, hi+lo = 32 KiB): batched sc0 sc1 loads
    u32x4 dh[4], dl[4];
#pragma unroll
    for (int jj = 0; jj < 4; ++jj) ld_x4_cc(&dh[jj], hsHi + (size_t)(jj * 256 + tid) * 8);
#pragma unroll
    for (int jj = 0; jj < 4; ++jj) ld_x4_cc(&dl[jj], hsLo + (size_t)(jj * 256 + tid) * 8);
    asm volatile("s_waitcnt vmcnt(0)" ::: "memory");
    __builtin_amdgcn_sched_barrier(0);
#pragma unroll
    for (int jj = 0; jj < 4; ++jj) { asm volatile("" : "+v"(dh[jj])); asm volatile("" : "+v"(dl[jj])); }
#pragma unroll
    for (int jj = 0; jj < 4; ++jj) {
      int gidx = jj * 256 + tid;
      int row = gidx >> 6, kq = gidx & 63;
      int kqs = (kq & ~7) | ((kq & 7) ^ (row & 7));
      *(u32x4*)(Hh + row * 512 + kqs * 8) = dh[jj];
      *(u32x4*)(Hl + row * 512 + kqs * 8) = dl[jj];
    }
    __syncthreads();

    // MFMA: 3-pass bf16 hi/lo: acc = p + Ah*Bh + Al*Bh + Ah*Bl
    const int br = wv * 16 + wi;  // B row in W LDS
#pragma unroll 4
    for (int ks = 0; ks < 16; ++ks) {
      int kq = ks * 4 + hi4;
      int kqsA = (kq & ~7) | ((kq & 7) ^ (wi & 7));
      int kqsB = (kq & ~7) | ((kq & 7) ^ (br & 7));
      short8 ah = *(const short8*)(Hh + wi * 512 + kqsA * 8);
      short8 al = *(const short8*)(Hl + wi * 512 + kqsA * 8);
      short8 bh = *(const short8*)(WhiL + br * 512 + kqsB * 8);
      short8 bl = *(const short8*)(WloL + br * 512 + kqsB * 8);
      accA = __builtin_amdgcn_mfma_f32_16x16x32_bf16(ah, bh, accA, 0, 0, 0);
      accB = __builtin_amdgcn_mfma_f32_16x16x32_bf16(al, bh, accB, 0, 0, 0);
      accC = __builtin_amdgcn_mfma_f32_16x16x32_bf16(ah, bl, accC, 0, 0, 0);
    }

    // gate combine (quad butterfly, verified rounds 1-2), pointwise
    const bool qb0 = (q & 1) != 0, qb1 = (q & 2) != 0;
    const int b = bg * 16 + hi4 * 4 + q;
    f4 a0;
#pragma unroll
    for (int j = 0; j < 4; ++j) a0[j] = accA[j] + accB[j] + accC[j];
    f4 x1, s1a, s1b, x2a, x2b;
#pragma unroll
    for (int j = 0; j < 4; ++j) x1[j] = __shfl_xor(a0[j], 1);
#pragma unroll
    for (int j = 0; j < 4; ++j) {
      s1a[j] = qb0 ? x1[j] : a0[j];
      s1b[j] = qb0 ? a0[j] : x1[j];
    }
#pragma unroll
    for (int j = 0; j < 4; ++j) {
      x2a[j] = __shfl_xor(s1a[j], 2);
      x2b[j] = __shfl_xor(s1b[j], 2);
    }
    f4 cn, hn;
#pragma unroll
    for (int j = 0; j < 4; ++j) {
      float gi = qb1 ? x2a[j] : s1a[j];
      float gg = qb1 ? s1a[j] : x2a[j];
      float gf = qb1 ? x2b[j] : s1b[j];
      float go = qb1 ? s1b[j] : x2b[j];
      float iv = sigmoidf_(gi);
      float fv = sigmoidf_(gf);
      float gv = tanhf_(gg);
      float ov = sigmoidf_(go);
      float c2 = fv * c_reg[j] + iv * gv;
      cn[j] = c2;
      hn[j] = ov * tanhf_(c2);
    }
    c_reg = cn;
    float s01 = qb0 ? hn[1] : hn[0];
    float s23 = qb0 ? hn[3] : hn[2];
    float hq = qb1 ? s23 : s01;

    // publish h first (hi/lo u16 at L3), drain, barrier, flag; out store AFTER flag
    uint16_t hhi = f2bf(hq);
    uint16_t hlo = f2bf(hq - bf2f(hhi));
    const int rowloc = hi4 * 4 + q;
    st_u16_cc(hdHi + (size_t)rowloc * 512 + u, (uint32_t)hhi);
    st_u16_cc(hdLo + (size_t)rowloc * 512 + u, (uint32_t)hlo);
    asm volatile("s_waitcnt vmcnt(0)" ::: "memory");  // h stores at coherence point
    __syncthreads();                                   // all waves' stores done
    if (tid == 0) st_flag_cc(myflag, s);
    __builtin_nontemporal_store(hq, &out[(size_t)b * (T_ * H_) + (size_t)(s - 1) * H_ + u]);
  }

  // persist c for chunked launches
  {
    const bool qb0 = (q & 1) != 0, qb1 = (q & 2) != 0;
    const int b = bg * 16 + hi4 * 4 + q;
    float c01 = qb0 ? c_reg[1] : c_reg[0];
    float c23 = qb0 ? c_reg[3] : c_reg[2];
    c_state[(size_t)b * H_ + u] = qb1 ? c23 : c01;
  }
}

extern "C" void kernel_launch(void* const* d_in, const int* in_sizes, int n_in,
                              void* d_out, int out_size, void* d_ws, size_t ws_size,
                              hipStream_t stream) {
  (void)in_sizes; (void)n_in; (void)out_size;
  const int* x = (const int*)d_in[0];
  const float* h0 = (const float*)d_in[1];
  const float* c0 = (const float*)d_in[2];
  const float* emb = (const float*)d_in[3];
  const float* Wih = (const float*)d_in[4];
  const float* Whh = (const float*)d_in[5];
  const float* bih = (const float*)d_in[6];
  const float* bhh = (const float*)d_in[7];
  float* out = (float*)d_out;
  char* ws = (char*)d_ws;

  int* flags = (int*)ws;                          // 512 B (padded to 4 KiB)
  float* c_state = (float*)(ws + 4096);           // 128 KiB
  uint16_t* hHi0 = (uint16_t*)(ws + 135168);      // 4 x 64 KiB h hi/lo double buffers
  uint16_t* hHi1 = (uint16_t*)(ws + 135168 + 65536);
  uint16_t* hLo0 = (uint16_t*)(ws + 135168 + 2 * 65536);
  uint16_t* hLo1 = (uint16_t*)(ws + 135168 + 3 * 65536);
  uint16_t* Whi_g = (uint16_t*)(ws + 397312);     // 2 MiB
  uint16_t* Wlo_g = (uint16_t*)(ws + 2494464);    // 2 MiB
  float* pre2 = (float*)(ws + 4591616);           // TB*32*4*1024 fp32

  int TB = 512;
  while (TB > 2 && (size_t)4591616 + (size_t)TB * 524288 > ws_size) TB >>= 1;

  (void)hipFuncSetAttribute(reinterpret_cast<const void*>(k_lstm),
                            hipFuncAttributeMaxDynamicSharedMemorySize, 163840);

  k_prep<<<dim3(4096), dim3(256), 0, stream>>>(Whh, Whi_g, Wlo_g);
  k_init<<<dim3(128), dim3(256), 0, stream>>>(h0, hHi0, hLo0, flags);
  for (int t0 = 0; t0 < 512; t0 += TB) {
    k_pre<<<dim3((TB * 64 / 128) * 16), dim3(256), 0, stream>>>(x, emb, Wih, bih, bhh, pre2, t0);
    k_lstm<<<dim3(128), dim3(256), 163840, stream>>>(pre2, Whi_g, Wlo_g, c0, out, hHi0, hHi1,
                                                     hLo0, hLo1, c_state, flags, t0, TB);
  }
}